// Round 3
// baseline (1203.379 us; speedup 1.0000x reference)
//
#include <hip/hip_runtime.h>
#include <stdint.h>

#define NN 50000
#define RR 64
#define EE 20000
#define NB 16            // bases
#define IND 256
#define OUTD 256
#define KK 4352          // 16*256 (V) + 256 (x for root)
#define NE (RR * EE)     // 1,280,000 edges
#define CHUNK 25600      // dst rows per V chunk (2 chunks)

typedef __attribute__((ext_vector_type(8))) short bf16x8;
typedef __attribute__((ext_vector_type(4))) float f32x4;

__device__ __forceinline__ unsigned short f2bf(float f) {
  union { float f; unsigned u; } v; v.f = f;
  unsigned r = v.u + 0x7FFFu + ((v.u >> 16) & 1u);   // RNE
  return (unsigned short)(r >> 16);
}

// ---------- sort phase: counting sort of all edges by dst ----------
__global__ __launch_bounds__(256) void k_hist(const int* __restrict__ edst,
                                              int* __restrict__ cnt) {
  const int g = blockIdx.x * 256 + threadIdx.x;      // grid covers NE exactly
  atomicAdd(&cnt[edst[g]], 1);
}

__global__ __launch_bounds__(1024) void k_scan(const int* __restrict__ cnt,
                                               int* __restrict__ rowptr,
                                               int* __restrict__ wof) {
  __shared__ int ps[1024];
  const int t = threadIdx.x;
  const int base = t * 49;                           // 49*1024 = 50176 >= NN
  int sum = 0;
  for (int j = 0; j < 49; ++j) { const int idx = base + j; if (idx < NN) sum += cnt[idx]; }
  ps[t] = sum; __syncthreads();
  for (int off = 1; off < 1024; off <<= 1) {         // inclusive Hillis-Steele
    int v = (t >= off) ? ps[t - off] : 0;
    __syncthreads();
    ps[t] += v;
    __syncthreads();
  }
  int run = ps[t] - sum;                             // exclusive prefix for this chunk
  for (int j = 0; j < 49; ++j) {
    const int idx = base + j;
    if (idx < NN) { rowptr[idx] = run; wof[idx] = run; run += cnt[idx]; }
  }
  if (t == 1023) rowptr[NN] = ps[1023];
}

__global__ __launch_bounds__(256) void k_scatter(const int* __restrict__ esrc,
                                                 const int* __restrict__ edst,
                                                 int* __restrict__ wof,
                                                 unsigned* __restrict__ payload) {
  const int g = blockIdx.x * 256 + threadIdx.x;
  const int d = edst[g];
  const int src = esrc[g];
  const int r = g / EE;                              // relation id
  const int pos = atomicAdd(&wof[d], 1);
  payload[pos] = ((unsigned)r << 18) | (unsigned)src;   // src < 2^17, r < 64
}

// ---------- bt[o][k] = B^T bf16: k<4096 -> basis[k/256][k%256][o]; else root[k-4096][o] ----------
__global__ __launch_bounds__(256) void k_bt(const float* __restrict__ basis,
                                            const float* __restrict__ root,
                                            unsigned short* __restrict__ bt) {
  const int o = blockIdx.x;
  for (int k = threadIdx.x; k < KK; k += 256) {
    float v;
    if (k < 4096) v = basis[(size_t)k * 256 + o];    // (b*256+i)*256+o == k*256+o
    else          v = root[(size_t)(k - 4096) * 256 + o];
    bt[(size_t)o * KK + k] = f2bf(v);
  }
}

// ---------- V-build: one wave per dst; V[n,b,i] = (1/deg) * sum_e att[r_e,b]*x[src_e,i] ----------
__global__ __launch_bounds__(256) void k_vbuild(
    const float* __restrict__ x, const float* __restrict__ att,
    const float* __restrict__ deg, const int* __restrict__ rowptr,
    const unsigned* __restrict__ payload, unsigned short* __restrict__ Vb,
    const int c0) {
  const int t = threadIdx.x;
  const int lane = t & 63;
  const int n = c0 + blockIdx.x * 4 + (t >> 6);      // one wave per dst row
  if (n >= NN) return;
  const int k0 = rowptr[n], k1 = rowptr[n + 1];
  float acc[NB][4];
#pragma unroll
  for (int b = 0; b < NB; ++b)
#pragma unroll
    for (int q = 0; q < 4; ++q) acc[b][q] = 0.f;

  if (k0 < k1) {
    unsigned pk = payload[k0];
    float4 xv = *reinterpret_cast<const float4*>(
        x + (size_t)(pk & 0x3FFFFu) * IND + lane * 4);
    for (int k = k0; k < k1; ++k) {
      unsigned pk_n = 0u;
      float4 xv_n = make_float4(0.f, 0.f, 0.f, 0.f);
      if (k + 1 < k1) {                              // prefetch next edge's x row
        pk_n = payload[k + 1];
        xv_n = *reinterpret_cast<const float4*>(
            x + (size_t)(pk_n & 0x3FFFFu) * IND + lane * 4);
      }
      const float* ar = att + (pk >> 18) * NB;       // wave-uniform -> scalar loads
#pragma unroll
      for (int b = 0; b < NB; ++b) {
        const float av = ar[b];
        acc[b][0] = fmaf(av, xv.x, acc[b][0]);
        acc[b][1] = fmaf(av, xv.y, acc[b][1]);
        acc[b][2] = fmaf(av, xv.z, acc[b][2]);
        acc[b][3] = fmaf(av, xv.w, acc[b][3]);
      }
      pk = pk_n; xv = xv_n;
    }
  }
  const float iv = 1.0f / deg[n];
  unsigned short* vr = Vb + (size_t)(n - c0) * 4096 + lane * 4;
#pragma unroll
  for (int b = 0; b < NB; ++b) {
    ushort4 s;
    s.x = f2bf(acc[b][0] * iv); s.y = f2bf(acc[b][1] * iv);
    s.z = f2bf(acc[b][2] * iv); s.w = f2bf(acc[b][3] * iv);
    *reinterpret_cast<ushort4*>(vr + (size_t)b * 256) = s;
  }
}

// ---------- GEMM: out_rows = [V/deg | x_bf16] @ bt^T ; 64 rows x 128 cols per block ----------
__global__ __launch_bounds__(256) void k_gemm(
    const float* __restrict__ x, const unsigned short* __restrict__ Vb,
    const unsigned short* __restrict__ bt, float* __restrict__ out,
    const int c0) {
  __shared__ unsigned short Al[64 * 64];             // 8 KB, XOR chunk-swizzled
  const int t = threadIdx.x;
  const int rb = blockIdx.x, cb = blockIdx.y;
  const int lane = t & 63, w = t >> 6;
  const int wr = w >> 1, wc = w & 1;                 // 2x2 waves of 32x64
  const int lc = lane & 15, lg = lane >> 4;
  f32x4 acc[2][4];
  const f32x4 zf = {0.f, 0.f, 0.f, 0.f};
#pragma unroll
  for (int m = 0; m < 2; ++m)
#pragma unroll
    for (int nn = 0; nn < 4; ++nn) acc[m][nn] = zf;

  const int row_s = t >> 2, c4 = t & 3;              // staging role: 4 threads/row
  const int n_s = c0 + rb * 64 + row_s;
  const bool ok_s = n_s < NN;

  for (int it = 0; it < 68; ++it) {                  // 68 * 64 = 4352 = KK
    __syncthreads();                                 // Al reuse protection
    union { bf16x8 v; unsigned short u[8]; } p0, p1;
    if (it < 64) {
      if (ok_s) {
        const unsigned short* src = Vb + (size_t)(n_s - c0) * 4096 + it * 64 + c4 * 16;
        p0.v = *reinterpret_cast<const bf16x8*>(src);
        p1.v = *reinterpret_cast<const bf16x8*>(src + 8);
      } else {
#pragma unroll
        for (int q = 0; q < 8; ++q) { p0.u[q] = 0; p1.u[q] = 0; }
      }
    } else {
      if (ok_s) {
        const float* xs = x + (size_t)n_s * IND + (it - 64) * 64 + c4 * 16;
#pragma unroll
        for (int q = 0; q < 8; ++q) { p0.u[q] = f2bf(xs[q]); p1.u[q] = f2bf(xs[8 + q]); }
      } else {
#pragma unroll
        for (int q = 0; q < 8; ++q) { p0.u[q] = 0; p1.u[q] = 0; }
      }
    }
    const int ch0 = c4 * 2, ch1 = c4 * 2 + 1;
    *reinterpret_cast<bf16x8*>(&Al[row_s * 64 + ((ch0 ^ (row_s & 7)) * 8)]) = p0.v;
    *reinterpret_cast<bf16x8*>(&Al[row_s * 64 + ((ch1 ^ (row_s & 7)) * 8)]) = p1.v;
    __syncthreads();
#pragma unroll
    for (int kk = 0; kk < 2; ++kk) {
      bf16x8 af[2], bfr[4];
#pragma unroll
      for (int m = 0; m < 2; ++m) {
        const int ar = wr * 32 + m * 16 + lc;
        const int ch = kk * 4 + lg;
        af[m] = *reinterpret_cast<const bf16x8*>(&Al[ar * 64 + ((ch ^ (ar & 7)) * 8)]);
      }
#pragma unroll
      for (int nn = 0; nn < 4; ++nn) {
        const int o = cb * 128 + wc * 64 + nn * 16 + lc;
        bfr[nn] = *reinterpret_cast<const bf16x8*>(
            &bt[(size_t)o * KK + it * 64 + kk * 32 + lg * 8]);
      }
#pragma unroll
      for (int m = 0; m < 2; ++m)
#pragma unroll
        for (int nn = 0; nn < 4; ++nn)
          acc[m][nn] = __builtin_amdgcn_mfma_f32_16x16x32_bf16(af[m], bfr[nn], acc[m][nn], 0, 0, 0);
    }
  }
#pragma unroll
  for (int m = 0; m < 2; ++m) {
#pragma unroll
    for (int j = 0; j < 4; ++j) {
      const int n = c0 + rb * 64 + wr * 32 + m * 16 + lg * 4 + j;
      if (n < NN) {
        float* orow = out + (size_t)n * OUTD + cb * 128 + wc * 64 + lc;
        orow[0]  = acc[m][0][j];
        orow[16] = acc[m][1][j];
        orow[32] = acc[m][2][j];
        orow[48] = acc[m][3][j];
      }
    }
  }
}

extern "C" void kernel_launch(void* const* d_in, const int* in_sizes, int n_in,
                              void* d_out, int out_size, void* d_ws, size_t ws_size,
                              hipStream_t stream) {
  (void)in_sizes; (void)n_in; (void)out_size; (void)ws_size;
  const float* x     = (const float*)d_in[0];
  const float* att   = (const float*)d_in[1];
  const float* basis = (const float*)d_in[2];
  const float* root  = (const float*)d_in[3];
  const float* deg   = (const float*)d_in[4];
  const int*   esrc  = (const int*)d_in[5];
  const int*   edst  = (const int*)d_in[6];
  float* out = (float*)d_out;

  char* p = (char*)d_ws;
  unsigned short* Vb = (unsigned short*)p; p += (size_t)CHUNK * 4096 * 2;   // 209.7 MB
  unsigned short* bt = (unsigned short*)p; p += (size_t)OUTD * KK * 2;      // 2.23 MB
  unsigned* payload  = (unsigned*)p;       p += (size_t)NE * 4;             // 5.12 MB
  int* rowptr        = (int*)p;            p += (size_t)(NN + 1) * 4;
  int* wof           = (int*)p;            p += (size_t)NN * 4;
  int* cnt           = (int*)p;            p += (size_t)NN * 4;

  hipMemsetAsync(cnt, 0, (size_t)NN * 4, stream);
  hipLaunchKernelGGL(k_hist,    dim3(NE / 256), dim3(256),  0, stream, edst, cnt);
  hipLaunchKernelGGL(k_scan,    dim3(1),        dim3(1024), 0, stream, cnt, rowptr, wof);
  hipLaunchKernelGGL(k_scatter, dim3(NE / 256), dim3(256),  0, stream, esrc, edst, wof, payload);
  hipLaunchKernelGGL(k_bt,      dim3(OUTD),     dim3(256),  0, stream, basis, root, bt);

  for (int c = 0; c < 2; ++c) {
    const int c0 = c * CHUNK;
    hipLaunchKernelGGL(k_vbuild, dim3(CHUNK / 4), dim3(256), 0, stream,
                       x, att, deg, rowptr, payload, Vb, c0);
    hipLaunchKernelGGL(k_gemm, dim3(CHUNK / 64, 2), dim3(256), 0, stream,
                       x, Vb, bt, out, c0);
  }
}

// Round 4
// 976.588 us; speedup vs baseline: 1.2322x; 1.2322x over previous
//
#include <hip/hip_runtime.h>
#include <stdint.h>

#define NN 50000
#define RR 64
#define EE 20000
#define NB 16            // bases
#define IND 256
#define OUTD 256
#define KK 4352          // 16*256 (V) + 256 (x for root)
#define NE (RR * EE)     // 1,280,000 edges
#define CHUNK 12800      // dst rows per V chunk (4 chunks)
#define NCHUNK 4
#define GITER 68         // KK / 64

typedef __attribute__((ext_vector_type(8))) short bf16x8;
typedef __attribute__((ext_vector_type(4))) float f32x4;

__device__ __forceinline__ unsigned short f2bf(float f) {
  union { float f; unsigned u; } v; v.f = f;
  unsigned r = v.u + 0x7FFFu + ((v.u >> 16) & 1u);   // RNE
  return (unsigned short)(r >> 16);
}
__device__ __forceinline__ float bf2f(unsigned short s) {
  union { unsigned u; float f; } v; v.u = ((unsigned)s) << 16;
  return v.f;
}

// ---------- x -> bf16 ----------
__global__ __launch_bounds__(256) void k_xbf(const float* __restrict__ x,
                                             unsigned short* __restrict__ xb) {
  const size_t g = (size_t)(blockIdx.x * 256 + threadIdx.x) * 8;
  float4 v0 = *reinterpret_cast<const float4*>(x + g);
  float4 v1 = *reinterpret_cast<const float4*>(x + g + 4);
  ushort4 o0 = {f2bf(v0.x), f2bf(v0.y), f2bf(v0.z), f2bf(v0.w)};
  ushort4 o1 = {f2bf(v1.x), f2bf(v1.y), f2bf(v1.z), f2bf(v1.w)};
  *reinterpret_cast<ushort4*>(xb + g) = o0;
  *reinterpret_cast<ushort4*>(xb + g + 4) = o1;
}

// ---------- counting sort of edges by dst ----------
__global__ __launch_bounds__(256) void k_hist(const int* __restrict__ edst,
                                              int* __restrict__ cnt) {
  const int g = blockIdx.x * 256 + threadIdx.x;
  atomicAdd(&cnt[edst[g]], 1);
}

__global__ __launch_bounds__(1024) void k_scan(const int* __restrict__ cnt,
                                               int* __restrict__ rowptr,
                                               int* __restrict__ wof) {
  __shared__ int ps[1024];
  const int t = threadIdx.x;
  const int base = t * 49;                           // 49*1024 >= NN
  int sum = 0;
  for (int j = 0; j < 49; ++j) { const int idx = base + j; if (idx < NN) sum += cnt[idx]; }
  ps[t] = sum; __syncthreads();
  for (int off = 1; off < 1024; off <<= 1) {
    int v = (t >= off) ? ps[t - off] : 0;
    __syncthreads();
    ps[t] += v;
    __syncthreads();
  }
  int run = ps[t] - sum;
  for (int j = 0; j < 49; ++j) {
    const int idx = base + j;
    if (idx < NN) { rowptr[idx] = run; wof[idx] = run; run += cnt[idx]; }
  }
  if (t == 1023) rowptr[NN] = ps[1023];
}

__global__ __launch_bounds__(256) void k_scatter(const int* __restrict__ esrc,
                                                 const int* __restrict__ edst,
                                                 int* __restrict__ wof,
                                                 unsigned* __restrict__ payload) {
  const int g = blockIdx.x * 256 + threadIdx.x;
  const int d = edst[g];
  const int src = esrc[g];
  const int r = g / EE;
  const int pos = atomicAdd(&wof[d], 1);
  payload[pos] = ((unsigned)r << 18) | (unsigned)src;
}

// ---------- bt[o][k] bf16: k<4096 -> basis[k][o] flat; else root[k-4096][o] ----------
__global__ __launch_bounds__(256) void k_bt(const float* __restrict__ basis,
                                            const float* __restrict__ root,
                                            unsigned short* __restrict__ bt) {
  const int o = blockIdx.x;
  for (int k = threadIdx.x; k < KK; k += 256) {
    float v;
    if (k < 4096) v = basis[(size_t)k * 256 + o];
    else          v = root[(size_t)(k - 4096) * 256 + o];
    bt[(size_t)o * KK + k] = f2bf(v);
  }
}

// ---------- V-build: one wave per dst; V[n,b,i] = (1/deg) * sum_e att[r_e,b]*x[src_e,i] ----------
__global__ __launch_bounds__(256) void k_vbuild(
    const unsigned short* __restrict__ xbf, const float* __restrict__ att,
    const float* __restrict__ deg, const int* __restrict__ rowptr,
    const unsigned* __restrict__ payload, unsigned short* __restrict__ Vb,
    const int c0) {
  __shared__ float attl[RR * NB];                    // 4 KB
  const int t = threadIdx.x;
  *reinterpret_cast<float4*>(&attl[t * 4]) =
      *reinterpret_cast<const float4*>(&att[t * 4]); // 1024 floats, 4/thread
  __syncthreads();
  const int lane = t & 63;
  const int n = c0 + blockIdx.x * 4 + (t >> 6);
  if (n >= NN) return;
  const int k0 = rowptr[n], k1 = rowptr[n + 1];
  float acc[NB][4];
#pragma unroll
  for (int b = 0; b < NB; ++b)
#pragma unroll
    for (int q = 0; q < 4; ++q) acc[b][q] = 0.f;

  unsigned pkA = 0, pkB = 0;
  ushort4 xvA = {0, 0, 0, 0}, xvB = {0, 0, 0, 0};
  if (k0 < k1) {
    pkA = payload[k0];
    xvA = *reinterpret_cast<const ushort4*>(xbf + (size_t)(pkA & 0x3FFFFu) * IND + lane * 4);
  }
  if (k0 + 1 < k1) {
    pkB = payload[k0 + 1];
    xvB = *reinterpret_cast<const ushort4*>(xbf + (size_t)(pkB & 0x3FFFFu) * IND + lane * 4);
  }
  for (int k = k0; k < k1; ++k) {
    unsigned pkC = 0; ushort4 xvC = {0, 0, 0, 0};
    if (k + 2 < k1) {                                // depth-2 prefetch
      pkC = payload[k + 2];
      xvC = *reinterpret_cast<const ushort4*>(xbf + (size_t)(pkC & 0x3FFFFu) * IND + lane * 4);
    }
    const int r = (int)(pkA >> 18);
    const float fx0 = bf2f(xvA.x), fx1 = bf2f(xvA.y), fx2 = bf2f(xvA.z), fx3 = bf2f(xvA.w);
#pragma unroll
    for (int b4 = 0; b4 < 4; ++b4) {
      const float4 a4 = *reinterpret_cast<const float4*>(&attl[r * NB + b4 * 4]);
      const float aa[4] = {a4.x, a4.y, a4.z, a4.w};
#pragma unroll
      for (int q = 0; q < 4; ++q) {
        float* ac = acc[b4 * 4 + q];
        ac[0] = fmaf(aa[q], fx0, ac[0]);
        ac[1] = fmaf(aa[q], fx1, ac[1]);
        ac[2] = fmaf(aa[q], fx2, ac[2]);
        ac[3] = fmaf(aa[q], fx3, ac[3]);
      }
    }
    pkA = pkB; xvA = xvB; pkB = pkC; xvB = xvC;
  }
  const float iv = 1.0f / deg[n];
  unsigned short* vr = Vb + (size_t)(n - c0) * 4096 + lane * 4;
#pragma unroll
  for (int b = 0; b < NB; ++b) {
    ushort4 s;
    s.x = f2bf(acc[b][0] * iv); s.y = f2bf(acc[b][1] * iv);
    s.z = f2bf(acc[b][2] * iv); s.w = f2bf(acc[b][3] * iv);
    *reinterpret_cast<ushort4*>(vr + (size_t)b * 256) = s;
  }
}

// ---------- GEMM: out = [V/deg | x] @ bt^T, 64x128 tile, 2 waves, dbuf LDS ----------
__global__ __launch_bounds__(128) void k_gemm2(
    const unsigned short* __restrict__ Vb, const unsigned short* __restrict__ xbf,
    const unsigned short* __restrict__ bt, float* __restrict__ out, const int c0) {
  __shared__ unsigned short As[2][64 * 64];          // 8 KB each
  __shared__ unsigned short Bs[2][128 * 64];         // 16 KB each
  const int t = threadIdx.x;
  const int rb = blockIdx.x, cb = blockIdx.y;
  const int lane = t & 63, w = t >> 6;
  const int lc = lane & 15, lg = lane >> 4;

  const int arow = t >> 1, ah = t & 1;               // A staging: 2 thr/row
  const int growl = rb * 64 + arow;                  // chunk-local row
  const int grow = c0 + growl;
  const bool okA = grow < NN;
  const unsigned short* btc = bt + (size_t)(cb * 128 + t) * KK;   // B staging: 1 thr/col

  bf16x8 ra[4], rbv[8];
  bf16x8 zv;
#pragma unroll
  for (int q = 0; q < 8; ++q) zv[q] = 0;

#define STAGE(IT)                                                                  \
  {                                                                                \
    const int it_ = (IT);                                                          \
    if (okA) {                                                                     \
      const unsigned short* asrc = (it_ < 64)                                      \
          ? Vb + (size_t)growl * 4096 + it_ * 64 + ah * 32                         \
          : xbf + (size_t)grow * 256 + (it_ - 64) * 64 + ah * 32;                  \
      _Pragma("unroll")                                                            \
      for (int j = 0; j < 4; ++j) ra[j] = *reinterpret_cast<const bf16x8*>(asrc + j * 8); \
    } else {                                                                       \
      _Pragma("unroll")                                                            \
      for (int j = 0; j < 4; ++j) ra[j] = zv;                                      \
    }                                                                              \
    const unsigned short* bsrc = btc + it_ * 64;                                   \
    _Pragma("unroll")                                                              \
    for (int j = 0; j < 8; ++j) rbv[j] = *reinterpret_cast<const bf16x8*>(bsrc + j * 8); \
  }

#define COMMIT(BUF)                                                                \
  {                                                                                \
    const int b_ = (BUF);                                                          \
    _Pragma("unroll")                                                              \
    for (int j = 0; j < 4; ++j) {                                                  \
      const int ch = ah * 4 + j;                                                   \
      *reinterpret_cast<bf16x8*>(&As[b_][arow * 64 + ((ch ^ (arow & 7)) * 8)]) = ra[j]; \
    }                                                                              \
    _Pragma("unroll")                                                              \
    for (int j = 0; j < 8; ++j)                                                    \
      *reinterpret_cast<bf16x8*>(&Bs[b_][t * 64 + ((j ^ (t & 7)) * 8)]) = rbv[j];  \
  }

  f32x4 acc[4][4];
  const f32x4 zf = {0.f, 0.f, 0.f, 0.f};
#pragma unroll
  for (int m = 0; m < 4; ++m)
#pragma unroll
    for (int n = 0; n < 4; ++n) acc[m][n] = zf;

  STAGE(0); COMMIT(0);
  int cur = 0;
  for (int it = 0; it < GITER; ++it) {
    __syncthreads();                                 // buf[cur] ready for all
    if (it + 1 < GITER) STAGE(it + 1);               // loads overlap MFMA below
#pragma unroll
    for (int kk = 0; kk < 2; ++kk) {
      bf16x8 af[4], bfm[4];
      const int ch = kk * 4 + lg;
#pragma unroll
      for (int m = 0; m < 4; ++m) {
        const int r2 = m * 16 + lc;
        af[m] = *reinterpret_cast<const bf16x8*>(&As[cur][r2 * 64 + ((ch ^ (r2 & 7)) * 8)]);
      }
#pragma unroll
      for (int n = 0; n < 4; ++n) {
        const int c2 = w * 64 + n * 16 + lc;
        bfm[n] = *reinterpret_cast<const bf16x8*>(&Bs[cur][c2 * 64 + ((ch ^ (c2 & 7)) * 8)]);
      }
#pragma unroll
      for (int m = 0; m < 4; ++m)
#pragma unroll
        for (int n = 0; n < 4; ++n)
          acc[m][n] = __builtin_amdgcn_mfma_f32_16x16x32_bf16(af[m], bfm[n], acc[m][n], 0, 0, 0);
    }
    if (it + 1 < GITER) { COMMIT(cur ^ 1); cur ^= 1; }
  }
#pragma unroll
  for (int m = 0; m < 4; ++m) {
#pragma unroll
    for (int j = 0; j < 4; ++j) {
      const int n = c0 + rb * 64 + m * 16 + lg * 4 + j;
      if (n < NN) {
        float* orow = out + (size_t)n * OUTD + cb * 128 + w * 64 + lc;
        orow[0]  = acc[m][0][j];
        orow[16] = acc[m][1][j];
        orow[32] = acc[m][2][j];
        orow[48] = acc[m][3][j];
      }
    }
  }
}

extern "C" void kernel_launch(void* const* d_in, const int* in_sizes, int n_in,
                              void* d_out, int out_size, void* d_ws, size_t ws_size,
                              hipStream_t stream) {
  (void)in_sizes; (void)n_in; (void)out_size; (void)ws_size;
  const float* x     = (const float*)d_in[0];
  const float* att   = (const float*)d_in[1];
  const float* basis = (const float*)d_in[2];
  const float* root  = (const float*)d_in[3];
  const float* deg   = (const float*)d_in[4];
  const int*   esrc  = (const int*)d_in[5];
  const int*   edst  = (const int*)d_in[6];
  float* out = (float*)d_out;

  char* p = (char*)d_ws;
  unsigned short* Vb  = (unsigned short*)p; p += (size_t)CHUNK * 4096 * 2;  // 104.9 MB
  unsigned short* xbf = (unsigned short*)p; p += (size_t)NN * IND * 2;      // 25.6 MB
  unsigned short* bt  = (unsigned short*)p; p += (size_t)OUTD * KK * 2;     // 2.2 MB
  unsigned* payload   = (unsigned*)p;       p += (size_t)NE * 4;            // 5.1 MB
  int* rowptr         = (int*)p;            p += (size_t)(NN + 1) * 4;
  int* wof            = (int*)p;            p += (size_t)NN * 4;
  int* cnt            = (int*)p;            p += (size_t)NN * 4;

  hipMemsetAsync(cnt, 0, (size_t)NN * 4, stream);
  hipLaunchKernelGGL(k_xbf,     dim3(NN * IND / 2048), dim3(256),  0, stream, x, xbf);
  hipLaunchKernelGGL(k_hist,    dim3(NE / 256),        dim3(256),  0, stream, edst, cnt);
  hipLaunchKernelGGL(k_scan,    dim3(1),               dim3(1024), 0, stream, cnt, rowptr, wof);
  hipLaunchKernelGGL(k_scatter, dim3(NE / 256),        dim3(256),  0, stream, esrc, edst, wof, payload);
  hipLaunchKernelGGL(k_bt,      dim3(OUTD),            dim3(256),  0, stream, basis, root, bt);

  for (int c = 0; c < NCHUNK; ++c) {
    const int c0 = c * CHUNK;
    hipLaunchKernelGGL(k_vbuild, dim3(CHUNK / 4), dim3(256), 0, stream,
                       xbf, att, deg, rowptr, payload, Vb, c0);
    hipLaunchKernelGGL(k_gemm2, dim3(CHUNK / 64, 2), dim3(128), 0, stream,
                       Vb, xbf, bt, out, c0);
  }
}